// Round 6
// baseline (2249.884 us; speedup 1.0000x reference)
//
#include <hip/hip_runtime.h>
#include <math.h>

#define NB 16
#define T  2048
#define D  512
#define BD 64
#define BT (NB*T)  // 32768

// workspace layout (float offsets)
#define OFF_K   0
#define OFF_V   (BT*BD)
#define OFF_Q   (2*BT*BD)
#define OFF_ETA (3*BT*BD)
#define OFF_H   (3*BT*BD + BT)
// total floats = 4*BT*BD + BT = 8,421,376  (~33.7 MB)

// gram scratch lives in d_out (64 MB; overwritten later by outproj):
// per 16-step chunk: KK[16*16] | KQ[16*16] | SC[16] | pad -> 544 floats
#define GSTRIDE 544
#define NCHUNK  (BT/16)   // 2048

// ---------------- DPP full-wave sum, result broadcast to all lanes ----------
__device__ __forceinline__ float wave_allsum(float x) {
  x += __int_as_float(__builtin_amdgcn_update_dpp(
      0, __float_as_int(x), 0x111, 0xf, 0xf, true));   // row_shr:1
  x += __int_as_float(__builtin_amdgcn_update_dpp(
      0, __float_as_int(x), 0x112, 0xf, 0xf, true));   // row_shr:2
  x += __int_as_float(__builtin_amdgcn_update_dpp(
      0, __float_as_int(x), 0x114, 0xf, 0xf, true));   // row_shr:4
  x += __int_as_float(__builtin_amdgcn_update_dpp(
      0, __float_as_int(x), 0x118, 0xf, 0xf, true));   // row_shr:8
  x += __int_as_float(__builtin_amdgcn_update_dpp(
      0, __float_as_int(x), 0x142, 0xa, 0xf, false));  // row_bcast:15 -> rows 1,3
  x += __int_as_float(__builtin_amdgcn_update_dpp(
      0, __float_as_int(x), 0x143, 0xc, 0xf, false));  // row_bcast:31 -> rows 2,3
  return __int_as_float(__builtin_amdgcn_readlane(__float_as_int(x), 63));
}

// DS-only barrier: waits lgkmcnt(0) (all loop lgkm ops are DS), leaves vmcnt
// in flight. Proven in r3/r4.
__device__ __forceinline__ void lds_barrier() {
  __builtin_amdgcn_sched_barrier(0);
  __builtin_amdgcn_s_waitcnt(0xC07F);  // vmcnt=63 (no wait), expcnt=7, lgkmcnt=0
  __builtin_amdgcn_s_barrier();
  __builtin_amdgcn_sched_barrier(0);
}

// ---------------- projection: K,V,Q = x @ W{k,v,q} + b ----------------
__device__ __forceinline__ void do_proj(const float* __restrict__ W,
                                        const float* __restrict__ bias,
                                        float* __restrict__ Out,
                                        const float* xs, int col, int rg,
                                        size_t row0) {
  float a0 = 0.f, a1 = 0.f, a2 = 0.f, a3 = 0.f;
  for (int d = 0; d < D; d += 4) {
    float w0 = W[(d + 0) * BD + col];
    float w1 = W[(d + 1) * BD + col];
    float w2 = W[(d + 2) * BD + col];
    float w3 = W[(d + 3) * BD + col];
    const float* xb = xs + (rg * 4) * D + d;
    float4 x0 = *(const float4*)(xb);
    float4 x1 = *(const float4*)(xb + D);
    float4 x2 = *(const float4*)(xb + 2 * D);
    float4 x3 = *(const float4*)(xb + 3 * D);
    a0 += x0.x * w0 + x0.y * w1 + x0.z * w2 + x0.w * w3;
    a1 += x1.x * w0 + x1.y * w1 + x1.z * w2 + x1.w * w3;
    a2 += x2.x * w0 + x2.y * w1 + x2.z * w2 + x2.w * w3;
    a3 += x3.x * w0 + x3.y * w1 + x3.z * w2 + x3.w * w3;
  }
  float bb = bias[col];
  Out[(row0 + rg * 4 + 0) * BD + col] = a0 + bb;
  Out[(row0 + rg * 4 + 1) * BD + col] = a1 + bb;
  Out[(row0 + rg * 4 + 2) * BD + col] = a2 + bb;
  Out[(row0 + rg * 4 + 3) * BD + col] = a3 + bb;
}

__global__ __launch_bounds__(256) void proj_kernel(
    const float* __restrict__ x,
    const float* __restrict__ Wk, const float* __restrict__ bk,
    const float* __restrict__ Wv, const float* __restrict__ bv,
    const float* __restrict__ Wq, const float* __restrict__ bq,
    float* __restrict__ Kout, float* __restrict__ Vout,
    float* __restrict__ Qout) {
  __shared__ __align__(16) float xs[16 * D];  // 32 KB
  const int tid = threadIdx.x;
  const size_t row0 = (size_t)blockIdx.x * 16;
  const float4* xg = (const float4*)(x + row0 * D);
  float4* xs4 = (float4*)xs;
#pragma unroll
  for (int i = 0; i < 8; i++) xs4[i * 256 + tid] = xg[i * 256 + tid];
  __syncthreads();
  const int col = tid & 63;
  const int rg = tid >> 6;  // 4 row-groups of 4 rows
  do_proj(Wk, bk, Kout, xs, col, rg, row0);
  do_proj(Wv, bv, Vout, xs, col, rg, row0);
  do_proj(Wq, bq, Qout, xs, col, rg, row0);
}

// ---------------- eta = sigmoid(x . lr_w + lr_b) ----------------
__global__ __launch_bounds__(256) void eta_kernel(const float* __restrict__ x,
                                                  const float* __restrict__ lr_w,
                                                  const float* __restrict__ lr_b,
                                                  float* __restrict__ eta) {
  const int tid = threadIdx.x;
  const int lane = tid & 63;
  const int wv = tid >> 6;
  const size_t r = (size_t)blockIdx.x * 4 + wv;  // one wave per row
  const float* xr = x + r * D + lane * 8;
  float4 a = *(const float4*)xr;
  float4 b = *(const float4*)(xr + 4);
  const float* lw = lr_w + lane * 8;
  float4 la = *(const float4*)lw;
  float4 lb = *(const float4*)(lw + 4);
  float p = a.x * la.x + a.y * la.y + a.z * la.z + a.w * la.w +
            b.x * lb.x + b.y * lb.y + b.z * lb.z + b.w * lb.w;
#pragma unroll
  for (int m = 32; m > 0; m >>= 1) p += __shfl_xor(p, m, 64);
  if (lane == 0) eta[r] = 1.0f / (1.0f + expf(-(p + lr_b[0])));
}

// ---------------- gram kernel: per 16-step chunk, precompute -------------
//   KK[i][t] = k_i . k_t ; KQ[i][t] = k_i . q_t ; SC[t] = sum g*(k+b-v)
__global__ __launch_bounds__(256) void gram_kernel(
    const float* __restrict__ K, const float* __restrict__ V,
    const float* __restrict__ Q, const float* __restrict__ ln_g,
    const float* __restrict__ ln_b, float* __restrict__ G) {
  __shared__ __align__(16) float sK[16][64], sQ[16][64], sV[16][64];
  __shared__ float sg[64], sb[64];
  const int tid = threadIdx.x;
  const size_t row0 = (size_t)blockIdx.x * 16;
  ((float4*)sK)[tid] = ((const float4*)(K + row0 * BD))[tid];
  ((float4*)sQ)[tid] = ((const float4*)(Q + row0 * BD))[tid];
  ((float4*)sV)[tid] = ((const float4*)(V + row0 * BD))[tid];
  if (tid < 64) { sg[tid] = ln_g[tid]; sb[tid] = ln_b[tid]; }
  __syncthreads();
  const int i = tid >> 4, t = tid & 15;
  float kk = 0.f, kq = 0.f;
#pragma unroll
  for (int d = 0; d < 64; d += 4) {
    float4 a4 = *(const float4*)&sK[i][d];
    float4 b4 = *(const float4*)&sK[t][d];
    float4 c4 = *(const float4*)&sQ[t][d];
    kk += a4.x * b4.x + a4.y * b4.y + a4.z * b4.z + a4.w * b4.w;
    kq += a4.x * c4.x + a4.y * c4.y + a4.z * c4.z + a4.w * c4.w;
  }
  size_t gb = (size_t)blockIdx.x * GSTRIDE;
  G[gb + i * 16 + t] = kk;
  G[gb + 256 + i * 16 + t] = kq;
  if (tid < 16) {
    float sc = 0.f;
    for (int d = 0; d < 64; d++)
      sc += sg[d] * (sK[tid][d] + sb[d] - sV[tid][d]);
    G[gb + 512 + tid] = sc;
  }
}

// ---------------- sequential TTT scan: chunked delta-rule ------------------
// Round 10: r5 (8-way split of ONE chain) regressed (1096->1563): lockstep
// sibling waves replicate the same serial chain and stall at the same points;
// extra barrier + flush gathers ate the rest. REVERT to r4's proven 4-wave
// structure, and fill the ~65% dependency-stall slots with an INDEPENDENT
// chain instead: TWO batch elements per block (waves 0-3 -> batch 2B,
// waves 4-7 -> batch 2B+1). Each SIMD hosts one wave of each group; when
// chain A stalls (rsqrt, DPP chain, readlane), chain B issues. Per-chain
// code/arithmetic is bit-identical to r4; the shared s_barrier couples two
// identically-shaped groups (minimal skew), still 2 barriers/chunk.
__global__ __launch_bounds__(512, 1)
void ttt_seq_kernel(
    const float* __restrict__ Kin, const float* __restrict__ Vin,
    const float* __restrict__ Qin, const float* __restrict__ eta_in,
    const float* __restrict__ W0, const float* __restrict__ ln_g,
    const float* __restrict__ ln_b, float* __restrict__ Hout,
    const float* __restrict__ gram) {
  __shared__ __align__(16) float2 part2[16][8][64];  // 64 KB (4 per group)
  __shared__ __align__(16) float kls[2][16][64];     // 8 KB
  __shared__ __align__(16) float qls[2][16][64];     // 8 KB
  const int tid = threadIdx.x;
  const int lane = tid & 63;
  const int w8 = __builtin_amdgcn_readfirstlane(tid) >> 6;  // 0..7
  const int grp = w8 >> 2;   // batch sub-group (0/1)
  const int wvu = w8 & 3;    // wave-in-group: owns W cols [16*wvu, 16*wvu+16)
  const int b = blockIdx.x * 2 + grp;

  // W slice: w[4i+j] = W0[lane*BD + 16*wvu + 4i+j]
  float w[16];
  {
    const float4* w04 = (const float4*)(W0 + (size_t)lane * BD + wvu * 16);
#pragma unroll
    for (int i = 0; i < 4; i++) {
      float4 t4 = w04[i];
      w[4 * i] = t4.x; w[4 * i + 1] = t4.y; w[4 * i + 2] = t4.z; w[4 * i + 3] = t4.w;
    }
  }
  const float g = ln_g[lane];
  const float bet = ln_b[lane];
  const float a = g * g;
  const float A2 = wave_allsum(a);

  size_t base = (size_t)b * T * BD;   // advances BD per step
  size_t ebase = (size_t)b * T;

  // per-lane rows of the current chunk (replicated in the 4 group waves;
  // reloaded in-place for chunk+1 during phase B)
  float krow[16], qrow[16], vrow[16];
#pragma unroll
  for (int r = 0; r < 16; r++) {
    krow[r] = Kin[base + r * BD + lane];
    qrow[r] = Qin[base + r * BD + lane];
    vrow[r] = Vin[base + r * BD + lane];
  }
  float ev  = eta_in[ebase + lane];
  float evn = eta_in[ebase + 64 + lane];

  float u2sv[4], qsv[4];  // deferred phase-2 state (4 owned steps per wave)

  for (int c64 = 0; c64 < 32; c64++) {
    size_t eoff = (size_t)(c64 + 2) * 64;
    if (eoff >= T) eoff = 0;
    float ev2 = eta_in[ebase + eoff + lane];

    for (int cc = 0; cc < 4; cc++) {
      // ---- gram loads for this chunk (consumed in phase B; phase A covers) --
      const size_t gb = (size_t)(b * 128 + c64 * 4 + cc) * GSTRIDE;
      float KKr[15], KQr[16];
#pragma unroll
      for (int t = 0; t < 15; t++) KKr[t] = gram[gb + t * 16 + lane];
#pragma unroll
      for (int t = 0; t < 16; t++) KQr[t] = gram[gb + 256 + t * 16 + lane];
      float SCv = gram[gb + 512 + lane];

      // ---- phase A: stage rows to LDS (group waves write identical values:
      // benign; each wave's own in-order DS writes make its reads correct) --
#pragma unroll
      for (int r = 0; r < 16; r++) {
        kls[grp][r][lane] = krow[r];
        qls[grp][r][lane] = qrow[r];
      }
      // 3-deep uniform-read pipeline (broadcast ds_read_b128, conflict-free)
      float4 kuf[3][4], quf[3][4];
#pragma unroll
      for (int r = 0; r < 3; r++) {
        const float4* kp = (const float4*)&kls[grp][r][wvu * 16];
        const float4* qp = (const float4*)&qls[grp][r][wvu * 16];
#pragma unroll
        for (int i = 0; i < 4; i++) { kuf[r][i] = kp[i]; quf[r][i] = qp[i]; }
      }
      float u0[16], p0[16];
#pragma unroll
      for (int r = 0; r < 16; r++) {
        const int bf = r % 3;
        float uu0 = 0.f, uu1 = 0.f, uu2 = 0.f, uu3 = 0.f;
        float pp0 = 0.f, pp1 = 0.f, pp2 = 0.f, pp3 = 0.f;
#pragma unroll
        for (int i = 0; i < 4; i++) {
          uu0 += kuf[bf][i].x * w[4 * i + 0];
          uu1 += kuf[bf][i].y * w[4 * i + 1];
          uu2 += kuf[bf][i].z * w[4 * i + 2];
          uu3 += kuf[bf][i].w * w[4 * i + 3];
          pp0 += quf[bf][i].x * w[4 * i + 0];
          pp1 += quf[bf][i].y * w[4 * i + 1];
          pp2 += quf[bf][i].z * w[4 * i + 2];
          pp3 += quf[bf][i].w * w[4 * i + 3];
        }
        part2[r][w8][lane] = make_float2((uu0 + uu1) + (uu2 + uu3),
                                         (pp0 + pp1) + (pp2 + pp3));
        if (r < 13) {
          const float4* kp = (const float4*)&kls[grp][r + 3][wvu * 16];
          const float4* qp = (const float4*)&qls[grp][r + 3][wvu * 16];
#pragma unroll
          for (int i = 0; i < 4; i++) { kuf[bf][i] = kp[i]; quf[bf][i] = qp[i]; }
        }
      }

      lds_barrier();  // partials visible

      // combine own group's partials -> full u, p
#pragma unroll
      for (int r = 0; r < 16; r++) {
        float2 pA = part2[r][grp * 4 + 0][lane];
        float2 pB = part2[r][grp * 4 + 1][lane];
        float2 pC = part2[r][grp * 4 + 2][lane];
        float2 pD = part2[r][grp * 4 + 3][lane];
        u0[r] = (pA.x + pB.x) + (pC.x + pD.x);
        p0[r] = (pA.y + pB.y) + (pC.y + pD.y);
      }

      // ---- phase B: 16 serial steps, no barriers ----
#pragma unroll
      for (int t = 0; t < 16; t++) {
        float u = u0[t];
        float kcur = krow[t], vcur = vrow[t], qcur = qrow[t];
        float ecur = __int_as_float(
            __builtin_amdgcn_readlane(__float_as_int(ev), cc * 16 + t));
        float c0 = g * (kcur + bet - vcur);

        float Su   = wave_allsum(u);
        float Suu  = wave_allsum(u * u);
        float Sau  = wave_allsum(a * u);
        float Sauu = wave_allsum(a * u * u);
        float Scu  = wave_allsum(c0 * u);
        float Sc   = __int_as_float(
            __builtin_amdgcn_readlane(__float_as_int(SCv), t));

        float mu = Su * (1.0f / 64);
        float var = Suu * (1.0f / 64) - mu * mu;
        float rstd = rsqrtf(var + 1e-6f);
        float xh = (u - mu) * rstd;
        float Axh   = rstd * (Sau - mu * A2);
        float Scxh  = rstd * (Scu - mu * Sc);
        float Saxh2 = rstd * rstd * (Sauu - 2.0f * mu * Sau + mu * mu * A2);
        float s1 = (2.0f / 64) * (Sc + Axh);
        float s2 = (2.0f / 64) * (Scxh + Saxh2);
        float dxh = (2.0f / 64) * (c0 + a * xh);
        float dldu = rstd * (dxh - s1 * (1.0f / 64) - xh * (s2 * (1.0f / 64)));
        float coef = -ecur * dldu;

        // critical correction first: u for step t+1
        if (t < 15)
          u0[t + 1] += coef * __int_as_float(
              __builtin_amdgcn_readlane(__float_as_int(KKr[t]), t + 1));
        // lazy corrections (off critical path; fill stall slots)
#pragma unroll
        for (int s = t + 2; s < 16; s++)
          u0[s] += coef * __int_as_float(
              __builtin_amdgcn_readlane(__float_as_int(KKr[t]), s));
#pragma unroll
        for (int s = t; s < 16; s++)
          p0[s] += coef * __int_as_float(
              __builtin_amdgcn_readlane(__float_as_int(KQr[t]), s));

        // W-slice update via uniform LDS read of row t (off critical path;
        // next use of w is next chunk's phase A)
        {
          const float4* kp = (const float4*)&kls[grp][t][wvu * 16];
#pragma unroll
          for (int i = 0; i < 4; i++) {
            float4 k4 = kp[i];
            w[4 * i + 0] += coef * k4.x;
            w[4 * i + 1] += coef * k4.y;
            w[4 * i + 2] += coef * k4.z;
            w[4 * i + 3] += coef * k4.w;
          }
        }

        if ((t & 3) == wvu) { u2sv[t >> 2] = p0[t]; qsv[t >> 2] = qcur; }

        // reload row t for the NEXT chunk (per-lane; 16 steps of cover)
        krow[t] = Kin[base + 16 * BD + lane];
        qrow[t] = Qin[base + 16 * BD + lane];
        vrow[t] = Vin[base + 16 * BD + lane];
        base += BD;
      }

      // ---- deferred phase-2 flush: each wave finalizes its 4 owned steps --
#pragma unroll
      for (int fi = 0; fi < 4; fi++) {
        float u2 = u2sv[fi];
        float Su2  = wave_allsum(u2);
        float Suu2 = wave_allsum(u2 * u2);
        float mu2 = Su2 * (1.0f / 64);
        float rstd2 = rsqrtf(Suu2 * (1.0f / 64) - mu2 * mu2 + 1e-6f);
        int tt = 4 * fi + wvu;
        Hout[base - (size_t)(16 - tt) * BD + lane] =
            qsv[fi] + (u2 - mu2) * rstd2 * g + bet;
      }

      // protect kls/qls/part2 (single-buffered) against next chunk's writes
      lds_barrier();
    }
    ev = evn; evn = ev2;
  }
}

// ---------------- out projection: z = H @ Wo + bo ----------------
__global__ __launch_bounds__(256) void outproj_kernel(
    const float* __restrict__ H, const float* __restrict__ Wo,
    const float* __restrict__ bo, float* __restrict__ out) {
  __shared__ __align__(16) float ht[16 * BD];  // 4 KB
  const int tid = threadIdx.x;
  const size_t row0 = (size_t)blockIdx.x * 16;
  ((float4*)ht)[tid] = ((const float4*)(H + row0 * BD))[tid];
  __syncthreads();
  float acc0[16], acc1[16];
#pragma unroll
  for (int r = 0; r < 16; r++) { acc0[r] = 0.f; acc1[r] = 0.f; }
  for (int kk = 0; kk < BD; kk++) {
    float w0 = Wo[kk * D + tid];
    float w1 = Wo[kk * D + tid + 256];
#pragma unroll
    for (int r = 0; r < 16; r++) {
      float hv = ht[r * BD + kk];
      acc0[r] += hv * w0;
      acc1[r] += hv * w1;
    }
  }
  float b0 = bo[tid], b1 = bo[tid + 256];
#pragma unroll
  for (int r = 0; r < 16; r++) {
    out[(row0 + r) * D + tid] = acc0[r] + b0;
    out[(row0 + r) * D + tid + 256] = acc1[r] + b1;
  }
}

extern "C" void kernel_launch(void* const* d_in, const int* in_sizes, int n_in,
                              void* d_out, int out_size, void* d_ws,
                              size_t ws_size, hipStream_t stream) {
  (void)in_sizes; (void)n_in; (void)out_size; (void)ws_size;
  const float* x    = (const float*)d_in[0];
  const float* Wk   = (const float*)d_in[1];
  const float* bk   = (const float*)d_in[2];
  const float* Wv   = (const float*)d_in[3];
  const float* bv   = (const float*)d_in[4];
  const float* Wq   = (const float*)d_in[5];
  const float* bq   = (const float*)d_in[6];
  const float* Wo   = (const float*)d_in[7];
  const float* bo   = (const float*)d_in[8];
  const float* ln_g = (const float*)d_in[9];
  const float* ln_b = (const float*)d_in[10];
  const float* lr_w = (const float*)d_in[11];
  const float* lr_b = (const float*)d_in[12];
  const float* W0   = (const float*)d_in[13];

  float* ws  = (float*)d_ws;
  float* Kb  = ws + OFF_K;
  float* Vb  = ws + OFF_V;
  float* Qb  = ws + OFF_Q;
  float* ETA = ws + OFF_ETA;
  float* Hb  = ws + OFF_H;
  float* out = (float*)d_out;
  float* GRAM = out;  // scratch inside d_out; overwritten later by outproj

  proj_kernel<<<BT / 16, 256, 0, stream>>>(x, Wk, bk, Wv, bv, Wq, bq, Kb, Vb, Qb);
  eta_kernel<<<BT / 4, 256, 0, stream>>>(x, lr_w, lr_b, ETA);
  gram_kernel<<<NCHUNK, 256, 0, stream>>>(Kb, Vb, Qb, ln_g, ln_b, GRAM);
  ttt_seq_kernel<<<NB / 2, 512, 0, stream>>>(Kb, Vb, Qb, ETA, W0, ln_g, ln_b, Hb, GRAM);
  outproj_kernel<<<BT / 16, 256, 0, stream>>>(Hb, Wo, bo, out);
}